// Round 7
// baseline (163.832 us; speedup 1.0000x reference)
//
#include <hip/hip_runtime.h>
#include <cstdint>
#include <cstddef>

#define NB   8
#define CIN  128
#define COUT 64
#define NPIX 131072
#define PLANE NPIX
#define LOG2E 1.44269504088896340736f

typedef _Float16 f16;
typedef _Float16 half4_t __attribute__((ext_vector_type(4)));
typedef _Float16 half8_t __attribute__((ext_vector_type(8)));
typedef short    bs8    __attribute__((ext_vector_type(8)));  // bf16x8 frag (bit pattern)
typedef float    float4_t __attribute__((ext_vector_type(4)));
typedef float    f32x16  __attribute__((ext_vector_type(16)));
typedef unsigned int uint2_t __attribute__((ext_vector_type(2)));

// float -> bf16 bits, RNE
__device__ __forceinline__ unsigned short f2bf(float f){
  unsigned u = __float_as_uint(f);
  return (unsigned short)((u + 0x7fffu + ((u >> 16) & 1u)) >> 16);
}

// ============ Kernel 1: 1x1 convs, 128-px dbuf tile; W converted in-reg (overlapped) ======
// Block 256 = 4 waves, grid 1024. Load schedule: issue 8x float4 x-loads (chunk A) FIRST,
// then 24x float4 W-loads -- all 32 in flight, one HBM round-trip (R2's regression was W
// serialized BEFORE x). Then: ldsA -> issue loadB -> sync -> computeA (hides B) -> ldsB
// -> sync -> computeB. W1 scaled by log2e at conversion (same RNE numerics as wsetup_k).
__global__ __launch_bounds__(256, 4) void conv_mfma_k(
    const float* __restrict__ x,
    const float* __restrict__ W1, const float* __restrict__ W2,
    const float* __restrict__ W3,
    f16* __restrict__ Qi, f16* __restrict__ Ki, unsigned short* __restrict__ V2)
{
  __shared__ __align__(16) f16 xs[2][64 * 136];  // 34.8 KB -> 4 blocks/CU

  int tid = threadIdx.x, lane = tid & 63, wv = tid >> 6;
  int l15 = lane & 15, q4 = lane >> 4;
  int b = blockIdx.x;
  int vb = (b & 7) * 128 + (b >> 3);             // bijective; image n = b&7 = XCD n
  int pxt = vb * 128;
  int n = pxt >> 14, hwt = pxt & 16383;

  int pxi = lane & 15, cg = lane >> 4;           // px-group 0..15, channel sub-group 0..3

  float4_t pre[2][4];
  auto load_regs = [&](int co) {
    #pragma unroll
    for (int s = 0; s < 2; ++s) {
      int c4 = s * 16 + wv * 4 + cg;             // 4-channel group 0..31
      const float* xp = x + ((size_t)(n * CIN + c4 * 4) << 14) + hwt + co + pxi * 4;
      pre[s][0] = *(const float4_t*)(xp);
      pre[s][1] = *(const float4_t*)(xp + 16384);
      pre[s][2] = *(const float4_t*)(xp + 32768);
      pre[s][3] = *(const float4_t*)(xp + 49152);
    }
  };
  auto write_lds = [&](int buf) {
    #pragma unroll
    for (int s = 0; s < 2; ++s) {
      int c4 = s * 16 + wv * 4 + cg;
      #pragma unroll
      for (int i = 0; i < 4; ++i) {
        half4_t h = { (f16)pre[s][0][i], (f16)pre[s][1][i],
                      (f16)pre[s][2][i], (f16)pre[s][3][i] };
        *(half4_t*)&xs[buf][(pxi * 4 + i) * 136 + c4 * 4] = h;
      }
    }
  };

  // ---- 1. issue chunk-A x loads (oldest in the vmcnt queue) ----
  load_regs(0);

  // ---- 2. W fp32 loads + f16 conversion; loads overlap chunk-A latency ----
  half8_t wq[4], wk[4], wvf[4];
  #pragma unroll
  for (int k0 = 0; k0 < 4; ++k0) {
    int rb = (wv * 16 + l15) * 128 + k0 * 32 + q4 * 8;
    float4_t a0 = *(const float4_t*)&W1[rb];
    float4_t a1 = *(const float4_t*)&W1[rb + 4];
    float4_t b0 = *(const float4_t*)&W2[rb];
    float4_t b1 = *(const float4_t*)&W2[rb + 4];
    float4_t c0 = *(const float4_t*)&W3[rb];
    float4_t c1 = *(const float4_t*)&W3[rb + 4];
    #pragma unroll
    for (int j = 0; j < 4; ++j) {
      wq[k0][j]      = (f16)(a0[j] * LOG2E);
      wq[k0][j + 4]  = (f16)(a1[j] * LOG2E);
      wk[k0][j]      = (f16)b0[j];
      wk[k0][j + 4]  = (f16)b1[j];
      wvf[k0][j]     = (f16)c0[j];
      wvf[k0][j + 4] = (f16)c1[j];
    }
  }

  auto compute = [&](int buf, int co) {
    #pragma unroll
    for (int mt = 0; mt < 4; ++mt) {
      float4_t cq = {0.f,0.f,0.f,0.f}, ck = {0.f,0.f,0.f,0.f}, cv = {0.f,0.f,0.f,0.f};
      #pragma unroll
      for (int k0 = 0; k0 < 4; ++k0) {
        half8_t xa = *(half8_t*)&xs[buf][(mt*16 + l15)*136 + k0*32 + q4*8];
        cq = __builtin_amdgcn_mfma_f32_16x16x32_f16(wq[k0],  xa, cq, 0, 0, 0); // D[cout][px]
        ck = __builtin_amdgcn_mfma_f32_16x16x32_f16(wk[k0],  xa, ck, 0, 0, 0); // D[cout][px]
        cv = __builtin_amdgcn_mfma_f32_16x16x32_f16(xa, wvf[k0], cv, 0, 0, 0); // D[px][cout]
      }
      int pxq = pxt + co + mt*16 + l15;          // Q/K: col = px
      int g   = wv*2 + (q4 >> 1);                // cout = wv*16 + q4*4 + r
      half4_t hq = {(f16)cq[0], (f16)cq[1], (f16)cq[2], (f16)cq[3]};
      half4_t hk = {(f16)ck[0], (f16)ck[1], (f16)ck[2], (f16)ck[3]};
      *(half4_t*)&Qi[((size_t)g * PLANE + pxq) * 8 + (q4 & 1)*4] = hq;
      *(half4_t*)&Ki[((size_t)g * PLANE + pxq) * 8 + (q4 & 1)*4] = hk;
      uint2_t pv;
      pv.x = (unsigned)f2bf(cv[0]) | ((unsigned)f2bf(cv[1]) << 16);
      pv.y = (unsigned)f2bf(cv[2]) | ((unsigned)f2bf(cv[3]) << 16);
      *(uint2_t*)&V2[(size_t)(wv*16 + l15) * PLANE + pxt + co + mt*16 + q4*4] = pv;
    }
  };

  // ---- 3. pipelined schedule (verbatim R5) ----
  write_lds(0);
  load_regs(64);           // chunk B in flight; hidden under computeA
  __syncthreads();
  compute(0, 0);
  write_lds(1);
  __syncthreads();
  compute(1, 64);
}

// ============ Kernel 2: attention, row-pair fused into 32x32 MFMA, zero LDS (R6) ============
__global__ __launch_bounds__(512, 4) void attn_fused_k(
    const f16* __restrict__ Qi, const f16* __restrict__ Ki,
    const unsigned short* __restrict__ V2, float* __restrict__ out)
{
  int tid = threadIdx.x, lane = tid & 63, wv = tid >> 6;
  int col = lane & 31, hsel = lane >> 5;          // col=(i,row) index; hsel = j-half
  int b = blockIdx.x;
  int img = b & 7;                                // image == XCD
  int p = b >> 3;                                 // 0..63
  int h0 = (p >> 1)*4 + (p & 1);                  // rows h0, h0+2 cover all h
  int h2 = h0 + 2;
  int seg = wv * 16;
  int nb = img << 14;

  // Q B-frags (hs-invariant): B[k16][n=col]; k16 = hsel*8+e from c-chunk g = 2k+hsel
  half8_t aq[4];
  {
    int pxn = nb + (((col < 16) ? h0 : h2) << 7) + seg + (col & 15);
    #pragma unroll
    for (int k = 0; k < 4; ++k)
      aq[k] = *(const half8_t*)&Qi[((size_t)(k*2 + hsel) * PLANE + pxn) * 8];
  }

  // w-direction validity bits per D-reg r: j = (r&3)+8*(r>>2)+4*hsel
  unsigned vbits = 0;
  {
    int iw = seg + (col & 15);
    #pragma unroll
    for (int r = 0; r < 16; ++r) {
      int jj = (r & 3) + 8*(r >> 2) + 4*hsel;
      int jw = seg - 8 + jj;
      int d  = jw - iw;
      bool val = (((d & 1) == 0) & (d >= -8) & (d <= 8) & ((unsigned)jw < 128u));
      vbits |= ((unsigned)val) << r;
    }
  }

  float s = 0.f;                                  // per-lane partial denominator (own n)
  f32x16 o0, o1;
  #pragma unroll
  for (int r = 0; r < 16; ++r) { o0[r] = 0.f; o1[r] = 0.f; }

  int lo = (h0 >= 8) ? (h0 - 8) : (h0 & 1);       // clamp, parity-preserving
  int hi = (h0 + 10 <= 127) ? (h0 + 10) : (126 + (h0 & 1));

  for (int hs = lo; hs <= hi; hs += 2) {
    int jb = nb + (hs << 7) + seg - 8;            // +-128B overrun stays in ws, masked

    half8_t bk[4];
    #pragma unroll
    for (int k = 0; k < 4; ++k)                   // A[m=col][k16=hsel*8+e], g = 2k+hsel
      bk[k] = *(const half8_t*)&Ki[((size_t)(k*2 + hsel) * PLANE + jb + col) * 8];
    bs8 bvv[2][2];
    #pragma unroll
    for (int ks = 0; ks < 2; ++ks)
      #pragma unroll
      for (int ct = 0; ct < 2; ++ct)              // B[k16=j][n=cout], 8 consecutive px
        bvv[ks][ct] = *(const bs8*)&V2[(size_t)(ct*32 + col) * PLANE + jb + ks*16 + hsel*8];

    f32x16 st;
    #pragma unroll
    for (int r = 0; r < 16; ++r) st[r] = 0.f;
    #pragma unroll
    for (int k = 0; k < 4; ++k)
      st = __builtin_amdgcn_mfma_f32_32x32x16_f16(bk[k], aq[k], st, 0, 0, 0);

    // row gate (vertical dh window) folds into the w-validity mask
    bool rok = (col < 16) ? (hs <= h0 + 8) : (hs >= h2 - 8);
    unsigned em = rok ? vbits : 0u;
    #pragma unroll
    for (int r = 0; r < 16; ++r) {
      st[r] = exp2f(((em >> r) & 1u) ? st[r] : -1e30f);
      s += st[r];
    }

    // P -> bf16 trunc pack (bias cancels in num/den); pairs are consecutive j
    unsigned pq[8];
    #pragma unroll
    for (int q = 0; q < 8; ++q)
      pq[q] = (__float_as_uint(st[2*q+1]) & 0xffff0000u) | (__float_as_uint(st[2*q]) >> 16);

    // redistribute j-halves across lane<32 / lane>=32: A-frag for PV
    uint2_t w0 = __builtin_amdgcn_permlane32_swap(pq[0], pq[2], false, false);
    uint2_t w1 = __builtin_amdgcn_permlane32_swap(pq[1], pq[3], false, false);
    uint2_t w2 = __builtin_amdgcn_permlane32_swap(pq[4], pq[6], false, false);
    uint2_t w3 = __builtin_amdgcn_permlane32_swap(pq[5], pq[7], false, false);
    unsigned pa0u[4] = { w0.x, w1.x, w0.y, w1.y };   // kstep0: j = hsel*8 + 0..7
    unsigned pa1u[4] = { w2.x, w3.x, w2.y, w3.y };   // kstep1: j = 16 + hsel*8 + 0..7
    bs8 pa0, pa1;
    #pragma unroll
    for (int q = 0; q < 4; ++q) {
      pa0[2*q]   = (short)(pa0u[q] & 0xffffu);
      pa0[2*q+1] = (short)(pa0u[q] >> 16);
      pa1[2*q]   = (short)(pa1u[q] & 0xffffu);
      pa1[2*q+1] = (short)(pa1u[q] >> 16);
    }

    o0 = __builtin_amdgcn_mfma_f32_32x32x16_bf16(pa0, bvv[0][0], o0, 0, 0, 0);
    o0 = __builtin_amdgcn_mfma_f32_32x32x16_bf16(pa1, bvv[1][0], o0, 0, 0, 0);
    o1 = __builtin_amdgcn_mfma_f32_32x32x16_bf16(pa0, bvv[0][1], o1, 0, 0, 0);
    o1 = __builtin_amdgcn_mfma_f32_32x32x16_bf16(pa1, bvv[1][1], o1, 0, 0, 0);
  }

  // epilogue: denominator = own-half sum + partner-half (same n, other j-half)
  float srow = s + __shfl_xor(s, 32, 64);
  int iw = seg + (col & 15);
  int wlo = iw - 8; if (wlo < 0) wlo = 0;
  int whi = iw + 8; if (whi > 127) whi = 127;
  int vw = ((whi - wlo) >> 1) + 1;
  int hr = (col < 16) ? h0 : h2;
  int hlo = hr - 8; if (hlo < 0) hlo = 0;
  int hhi = hr + 8; if (hhi > 127) hhi = 127;
  int vh = ((hhi - hlo) >> 1) + 1;
  float cnt = (float)(81 - vh * vw);              // OOB offsets contribute exp2(0)=1
  float sc = 1.f / (srow + cnt);

  // store: lane holds cout = ct*32+col; regs 4*gp+q -> m = 8*gp + 4*hsel + q
  #pragma unroll
  for (int ct = 0; ct < 2; ++ct) {
    const f32x16& o = ct ? o1 : o0;
    #pragma unroll
    for (int gp = 0; gp < 4; ++gp) {
      int m_base = 8*gp + 4*hsel;
      int hrow  = (m_base >> 4) ? h2 : h0;
      int i_b   = seg + (m_base & 15);
      float4_t stv;
      #pragma unroll
      for (int q = 0; q < 4; ++q)
        stv[q] = o[4*gp + q] * __shfl(sc, m_base + q, 64);
      size_t ob = ((size_t)(img*COUT + ct*32 + col) << 14) + (hrow << 7) + i_b;
      *(float4_t*)&out[ob] = stv;
    }
  }
}

// ---------------- launcher ----------------
extern "C" void kernel_launch(void* const* d_in, const int* in_sizes, int n_in,
                              void* d_out, int out_size, void* d_ws, size_t ws_size,
                              hipStream_t stream)
{
  const float* x  = (const float*)d_in[0];
  const float* W1 = (const float*)d_in[1];
  const float* W2 = (const float*)d_in[2];
  const float* W3 = (const float*)d_in[3];

  // ws: [64 KB guard] | Qi | Ki | V2 (~48 MB of 268 MB). +-128B edge overruns land
  // in the guard / adjacent array and are masked to zero weight before use.
  f16* Qi = (f16*)((char*)d_ws + 65536);             // [8][PLANE][8] f16 interleaved
  f16* Ki = Qi + (size_t)8 * PLANE * 8;              // [8][PLANE][8] f16
  unsigned short* V2 = (unsigned short*)(Ki + (size_t)8 * PLANE * 8); // [64][PLANE] bf16

  float* outp = (float*)d_out;

  conv_mfma_k <<<NPIX/128,  256, 0, stream>>>(x, W1, W2, W3, Qi, Ki, V2);
  attn_fused_k<<<NB*128/2,  512, 0, stream>>>(Qi, Ki, V2, outp);
}

// Round 8
// 153.615 us; speedup vs baseline: 1.0665x; 1.0665x over previous
//
#include <hip/hip_runtime.h>
#include <cstdint>
#include <cstddef>

#define NB   8
#define CIN  128
#define COUT 64
#define NPIX 131072
#define PLANE NPIX
#define LOG2E 1.44269504088896340736f

typedef _Float16 f16;
typedef _Float16 half4_t __attribute__((ext_vector_type(4)));
typedef _Float16 half8_t __attribute__((ext_vector_type(8)));
typedef short    bs8    __attribute__((ext_vector_type(8)));  // bf16x8 frag (bit pattern)
typedef float    float4_t __attribute__((ext_vector_type(4)));
typedef unsigned int uint2_t __attribute__((ext_vector_type(2)));

// float -> bf16 bits, RNE
__device__ __forceinline__ unsigned short f2bf(float f){
  unsigned u = __float_as_uint(f);
  return (unsigned short)((u + 0x7fffu + ((u >> 16) & 1u)) >> 16);
}

// ============ Kernel 0: pack W1|W2|W3 -> f16 [192][128]; W1 pre-scaled by log2e ============
// NOTE (R2/R7 evidence): folding this into conv costs +5-8us both times tried
// (W fp32 loads + 96 cvts contend with the staging pipeline at VGPR=64). Keep separate.
__global__ __launch_bounds__(256) void wsetup_k(
    const float* __restrict__ W1, const float* __restrict__ W2,
    const float* __restrict__ W3, f16* __restrict__ Wf)
{
  int idx = blockIdx.x * 256 + threadIdx.x;      // 0 .. 24575
  int mat = idx >> 13;
  int rem = idx & 8191;
  const float* src = (mat == 0 ? W1 : (mat == 1 ? W2 : W3));
  float v = src[rem];
  if (mat == 0) v *= LOG2E;                      // logits in base-2 -> exp2 in attn
  Wf[idx] = (f16)v;
}

// ============ Kernel 1: 1x1 convs, 128-px tile, double-buffered staging (R5, best) ========
// Block 256 = 4 waves, TWO 64-px chunks (A,B), grid 1024. Pipeline:
//   loadA -> ldsA -> issue loadB -> sync -> computeA (48 MFMA+stores hide B latency)
//   -> ldsB -> sync -> computeB.  W frags from f16 Wf (L2-hot), amortized over 128 px.
__global__ __launch_bounds__(256, 4) void conv_mfma_k(
    const float* __restrict__ x, const f16* __restrict__ Wf,
    f16* __restrict__ Qi, f16* __restrict__ Ki, unsigned short* __restrict__ V2)
{
  __shared__ __align__(16) f16 xs[2][64 * 136];  // 34.8 KB -> 4 blocks/CU

  int tid = threadIdx.x, lane = tid & 63, wv = tid >> 6;
  int l15 = lane & 15, q4 = lane >> 4;
  int b = blockIdx.x;
  int vb = (b & 7) * 128 + (b >> 3);             // bijective; image n = b&7 = XCD n
  int pxt = vb * 128;
  int n = pxt >> 14, hwt = pxt & 16383;

  int pxi = lane & 15, cg = lane >> 4;           // px-group 0..15, channel sub-group 0..3

  float4_t pre[2][4];
  auto load_regs = [&](int co) {
    #pragma unroll
    for (int s = 0; s < 2; ++s) {
      int c4 = s * 16 + wv * 4 + cg;             // 4-channel group 0..31
      const float* xp = x + ((size_t)(n * CIN + c4 * 4) << 14) + hwt + co + pxi * 4;
      pre[s][0] = *(const float4_t*)(xp);
      pre[s][1] = *(const float4_t*)(xp + 16384);
      pre[s][2] = *(const float4_t*)(xp + 32768);
      pre[s][3] = *(const float4_t*)(xp + 49152);
    }
  };
  auto write_lds = [&](int buf) {
    #pragma unroll
    for (int s = 0; s < 2; ++s) {
      int c4 = s * 16 + wv * 4 + cg;
      #pragma unroll
      for (int i = 0; i < 4; ++i) {
        half4_t h = { (f16)pre[s][0][i], (f16)pre[s][1][i],
                      (f16)pre[s][2][i], (f16)pre[s][3][i] };
        *(half4_t*)&xs[buf][(pxi * 4 + i) * 136 + c4 * 4] = h;
      }
    }
  };

  half8_t wq[4], wk[4], wvf[4];
  #pragma unroll
  for (int k0 = 0; k0 < 4; ++k0) {
    wq[k0]  = *(const half8_t*)&Wf[((wv     )*16 + l15)*128 + k0*32 + q4*8];
    wk[k0]  = *(const half8_t*)&Wf[((wv +  4)*16 + l15)*128 + k0*32 + q4*8];
    wvf[k0] = *(const half8_t*)&Wf[((wv +  8)*16 + l15)*128 + k0*32 + q4*8];
  }

  auto compute = [&](int buf, int co) {
    #pragma unroll
    for (int mt = 0; mt < 4; ++mt) {
      float4_t cq = {0.f,0.f,0.f,0.f}, ck = {0.f,0.f,0.f,0.f}, cv = {0.f,0.f,0.f,0.f};
      #pragma unroll
      for (int k0 = 0; k0 < 4; ++k0) {
        half8_t xa = *(half8_t*)&xs[buf][(mt*16 + l15)*136 + k0*32 + q4*8];
        cq = __builtin_amdgcn_mfma_f32_16x16x32_f16(wq[k0],  xa, cq, 0, 0, 0); // D[cout][px]
        ck = __builtin_amdgcn_mfma_f32_16x16x32_f16(wk[k0],  xa, ck, 0, 0, 0); // D[cout][px]
        cv = __builtin_amdgcn_mfma_f32_16x16x32_f16(xa, wvf[k0], cv, 0, 0, 0); // D[px][cout]
      }
      int pxq = pxt + co + mt*16 + l15;          // Q/K: col = px
      int g   = wv*2 + (q4 >> 1);                // cout = wv*16 + q4*4 + r
      half4_t hq = {(f16)cq[0], (f16)cq[1], (f16)cq[2], (f16)cq[3]};
      half4_t hk = {(f16)ck[0], (f16)ck[1], (f16)ck[2], (f16)ck[3]};
      *(half4_t*)&Qi[((size_t)g * PLANE + pxq) * 8 + (q4 & 1)*4] = hq;
      *(half4_t*)&Ki[((size_t)g * PLANE + pxq) * 8 + (q4 & 1)*4] = hk;
      uint2_t pv;
      pv.x = (unsigned)f2bf(cv[0]) | ((unsigned)f2bf(cv[1]) << 16);
      pv.y = (unsigned)f2bf(cv[2]) | ((unsigned)f2bf(cv[3]) << 16);
      *(uint2_t*)&V2[(size_t)(wv*16 + l15) * PLANE + pxt + co + mt*16 + q4*4] = pv;
    }
  };

  load_regs(0);
  write_lds(0);
  load_regs(64);           // chunk B in flight; hidden under computeA
  __syncthreads();
  compute(0, 0);
  write_lds(1);
  __syncthreads();
  compute(1, 64);
}

// ============ Kernel 2: fused flash local attention, row-paired, NO-MAX softmax (R5) ======
// Block 512 = 8 waves; wave = 16-px segment of rows (h0, h0+2) (shared K/V rows).
// Logits bounded -> exp2 without max subtraction is overflow-safe. Per hs:
// S^T = K.Q^T (f16 MFMA) -> mask -> exp2 -> partial sum + bf16 P (trunc pack) -> LDS ->
// O += P.V (bf16 MFMA). One normalize at end: sc = 1/(s + cnt_oob), OOB = exp2(0) = 1.
__global__ __launch_bounds__(512, 4) void attn_fused_k(
    const f16* __restrict__ Qi, const f16* __restrict__ Ki,
    const unsigned short* __restrict__ V2, float* __restrict__ out)
{
  __shared__ __align__(16) unsigned short plds[8][2][16 * 40];   // 20.5 KB

  int tid = threadIdx.x, lane = tid & 63, wv = tid >> 6;
  int l15 = lane & 15, q4 = lane >> 4;
  int b = blockIdx.x;
  int n = b & 7;                                  // XCD swizzle: image n -> XCD n
  int p = b >> 3;                                 // 0..63
  int h0 = (p >> 1)*4 + (p & 1);                  // rows h0, h0+2 cover all h
  int h2 = h0 + 2;
  int seg = wv * 16;
  int nb = n << 14;

  unsigned short* P0 = &plds[wv][0][0];
  unsigned short* P1 = &plds[wv][1][0];

  // Q B-frags for both rows (n-dim = i = l15)
  half8_t aq0[2], aq1[2];
  {
    int px0 = nb + (h0 << 7) + seg + l15;
    aq0[0] = *(const half8_t*)&Qi[((size_t)(q4    ) * PLANE + px0) * 8];
    aq0[1] = *(const half8_t*)&Qi[((size_t)(q4 + 4) * PLANE + px0) * 8];
    int px1 = px0 + 256;
    aq1[0] = *(const half8_t*)&Qi[((size_t)(q4    ) * PLANE + px1) * 8];
    aq1[1] = *(const half8_t*)&Qi[((size_t)(q4 + 4) * PLANE + px1) * 8];
  }

  // dh-invariant validity: bit jt*4+r; lane j = seg-8+jt*16+q4*4+r, i = seg+l15
  unsigned vbits = 0;
  #pragma unroll
  for (int jt = 0; jt < 2; ++jt)
    #pragma unroll
    for (int rr = 0; rr < 4; ++rr) {
      int jw = seg - 8 + jt*16 + q4*4 + rr;
      int iw = seg + l15;
      int d  = jw - iw;
      bool val = (((d & 1) == 0) & (d >= -8) & (d <= 8) & ((unsigned)jw < 128u));
      vbits |= ((unsigned)val) << (jt*4 + rr);
    }

  float s0 = 0.f, s1 = 0.f;                       // per-lane partial denominators
  float4_t o0[4], o1[4];
  #pragma unroll
  for (int ct = 0; ct < 4; ++ct) {
    o0[ct] = (float4_t){0.f,0.f,0.f,0.f};
    o1[ct] = (float4_t){0.f,0.f,0.f,0.f};
  }

  auto row_body = [&](const half8_t* aq, float& s_part,
                      float4_t* o, unsigned short* P,
                      const half8_t (&bk)[2][2], const bs8 (&bv)[4]) {
    float4_t st0 = (float4_t){0.f,0.f,0.f,0.f};
    float4_t st1 = (float4_t){0.f,0.f,0.f,0.f};
    st0 = __builtin_amdgcn_mfma_f32_16x16x32_f16(bk[0][0], aq[0], st0, 0, 0, 0);
    st0 = __builtin_amdgcn_mfma_f32_16x16x32_f16(bk[0][1], aq[1], st0, 0, 0, 0);
    st1 = __builtin_amdgcn_mfma_f32_16x16x32_f16(bk[1][0], aq[0], st1, 0, 0, 0);
    st1 = __builtin_amdgcn_mfma_f32_16x16x32_f16(bk[1][1], aq[1], st1, 0, 0, 0);
    // mask -> exp2 (masked lanes: exp2(-1e30) = 0)
    #pragma unroll
    for (int rr = 0; rr < 4; ++rr) {
      st0[rr] = exp2f(((vbits >> rr)       & 1u) ? st0[rr] : -1e30f);
      st1[rr] = exp2f(((vbits >> (4 + rr)) & 1u) ? st1[rr] : -1e30f);
    }
    s_part += (st0[0] + st0[1]) + (st0[2] + st0[3])
            + (st1[0] + st1[1]) + (st1[2] + st1[3]);
    // P -> bf16 trunc pack (bias cancels in num/den ratio), 2x b64 LDS writes
    uint2_t pk0, pk1;
    pk0.x = (__float_as_uint(st0[1]) & 0xffff0000u) | (__float_as_uint(st0[0]) >> 16);
    pk0.y = (__float_as_uint(st0[3]) & 0xffff0000u) | (__float_as_uint(st0[2]) >> 16);
    pk1.x = (__float_as_uint(st1[1]) & 0xffff0000u) | (__float_as_uint(st1[0]) >> 16);
    pk1.y = (__float_as_uint(st1[3]) & 0xffff0000u) | (__float_as_uint(st1[2]) >> 16);
    *(uint2_t*)&P[l15*40      + q4*4] = pk0;
    *(uint2_t*)&P[l15*40 + 16 + q4*4] = pk1;
    bs8 ap = *(bs8*)&P[l15*40 + q4*8];            // A-layout read (K=32 exact)
    #pragma unroll
    for (int ct = 0; ct < 4; ++ct)
      o[ct] = __builtin_amdgcn_mfma_f32_16x16x32_bf16(ap, bv[ct], o[ct], 0, 0, 0);
  };

  for (int hs = h0 - 8; hs <= h0 + 10; hs += 2) {
    if (hs < 0 || hs > 127) continue;              // wave-uniform
    int jbase = nb + (hs << 7) + seg - 8;          // +-128B overrun stays in ws, masked

    half8_t bk[2][2];
    #pragma unroll
    for (int jt = 0; jt < 2; ++jt) {
      int pxj = jbase + jt*16 + l15;
      bk[jt][0] = *(const half8_t*)&Ki[((size_t)(q4    ) * PLANE + pxj) * 8];
      bk[jt][1] = *(const half8_t*)&Ki[((size_t)(q4 + 4) * PLANE + pxj) * 8];
    }
    bs8 bv[4];
    #pragma unroll
    for (int ct = 0; ct < 4; ++ct)
      bv[ct] = *(const bs8*)&V2[(size_t)(ct*16 + l15) * PLANE + jbase + q4*8];

    if (hs <= h0 + 8) row_body(aq0, s0, o0, P0, bk, bv);
    if (hs >= h2 - 8) row_body(aq1, s1, o1, P1, bk, bv);
  }

  // epilogue: reduce s over q4, add OOB count, normalize, float4 store
  int iw = seg + l15;
  int wlo = iw - 8; if (wlo < 0) wlo = 0;
  int whi = iw + 8; if (whi > 127) whi = 127;
  int vw = ((whi - wlo) >> 1) + 1;
  #pragma unroll
  for (int row = 0; row < 2; ++row) {
    int hr = row ? h2 : h0;
    int hlo = hr - 8; if (hlo < 0) hlo = 0;
    int hhi = hr + 8; if (hhi > 127) hhi = 127;
    int vh = ((hhi - hlo) >> 1) + 1;
    float cnt = (float)(81 - vh * vw);
    float srow = row ? s1 : s0;
    srow += __shfl_xor(srow, 16, 64);
    srow += __shfl_xor(srow, 32, 64);              // row-sum for i = l15
    float sc = 1.f / (srow + cnt);
    float4_t scv;
    #pragma unroll
    for (int rr = 0; rr < 4; ++rr) scv[rr] = __shfl(sc, q4*4 + rr, 64);
    const float4_t* o = row ? o1 : o0;
    #pragma unroll
    for (int ct = 0; ct < 4; ++ct) {
      size_t ob = ((size_t)(n*COUT + ct*16 + l15) << 14) + (hr << 7) + seg + q4*4;
      float4_t stv;
      #pragma unroll
      for (int rr = 0; rr < 4; ++rr) stv[rr] = o[ct][rr] * scv[rr];
      *(float4_t*)&out[ob] = stv;
    }
  }
}

// ---------------- launcher ----------------
extern "C" void kernel_launch(void* const* d_in, const int* in_sizes, int n_in,
                              void* d_out, int out_size, void* d_ws, size_t ws_size,
                              hipStream_t stream)
{
  const float* x  = (const float*)d_in[0];
  const float* W1 = (const float*)d_in[1];
  const float* W2 = (const float*)d_in[2];
  const float* W3 = (const float*)d_in[3];

  // ws: Wf (48 KB, padded to 64 KB guard) | Qi | Ki | V2 (~48 MB of 268 MB).
  // +-128B edge overruns land in the guard / adjacent array, masked to zero weight.
  f16* Wf = (f16*)d_ws;                              // [192][128] f16
  f16* Qi = (f16*)((char*)d_ws + 65536);             // [8][PLANE][8] f16 interleaved
  f16* Ki = Qi + (size_t)8 * PLANE * 8;              // [8][PLANE][8] f16
  unsigned short* V2 = (unsigned short*)(Ki + (size_t)8 * PLANE * 8); // [64][PLANE] bf16

  float* outp = (float*)d_out;

  wsetup_k    <<<96,        256, 0, stream>>>(W1, W2, W3, Wf);
  conv_mfma_k <<<NPIX/128,  256, 0, stream>>>(x, Wf, Qi, Ki, V2);
  attn_fused_k<<<NB*128/2,  512, 0, stream>>>(Qi, Ki, V2, outp);
}